// Round 8
// baseline (791.768 us; speedup 1.0000x reference)
//
#include <hip/hip_runtime.h>
#include <hip/hip_cooperative_groups.h>
#include <stdint.h>

namespace cg = cooperative_groups;

// B=4, N=M=4096, C=256
#define CAP 128   // max matches kept per row (lambda~9.5; P(cnt>128) ~ 1e-80)

typedef __attribute__((ext_vector_type(4))) float f32x4;
typedef __attribute__((ext_vector_type(8))) short bf16x8;

__device__ __forceinline__ float bf2f(ushort u) {
  return __uint_as_float(((unsigned)u) << 16);
}
__device__ __forceinline__ ushort f2bf(float f) {
  unsigned u = __float_as_uint(f);
  return (ushort)((u + 0x7fffu + ((u >> 16) & 1u)) >> 16);  // RNE
}
__device__ __forceinline__ float wredsum(float v) {
#pragma unroll
  for (int o = 32; o; o >>= 1) v += __shfl_xor(v, o);
  return v;
}

// ---------------- GEMM body: Y[r,o] = sum_c A[r,c]*W[o,c] + bias[o] ----------------
template <bool A_BF16, typename OutT>
__device__ __forceinline__ void gemm_body(const void* __restrict__ Av,
                                          const float* __restrict__ Wf,
                                          const float* __restrict__ bias,
                                          OutT* __restrict__ Y, int blk,
                                          ushort* As, ushort* Bs) {
  int tid = threadIdx.x;
  int lane = tid & 63, wid = tid >> 6;
  int bm = blk >> 1, bn = blk & 1;
  int r0 = bm * 128, c0 = bn * 128;
  int wr = wid >> 1, wc = wid & 1;
  f32x4 acc[4][4] = {};
  for (int k0 = 0; k0 < 256; k0 += 32) {
    __syncthreads();
#pragma unroll
    for (int p = 0; p < 2; ++p) {
      int u = p * 2048 + tid * 8;
      int row = u >> 5, col = u & 31;
      if constexpr (A_BF16) {
        *(bf16x8*)&As[u] =
            *(const bf16x8*)((const ushort*)Av + (size_t)(r0 + row) * 256 + k0 + col);
      } else {
        const float* Af = (const float*)Av;
        float4 lo = *(const float4*)(Af + (size_t)(r0 + row) * 256 + k0 + col);
        float4 hi = *(const float4*)(Af + (size_t)(r0 + row) * 256 + k0 + col + 4);
        ushort4 o0 = { f2bf(lo.x), f2bf(lo.y), f2bf(lo.z), f2bf(lo.w) };
        ushort4 o1 = { f2bf(hi.x), f2bf(hi.y), f2bf(hi.z), f2bf(hi.w) };
        *(ushort4*)&As[u] = o0;
        *(ushort4*)&As[u + 4] = o1;
      }
      {
        float4 lo = *(const float4*)(Wf + (size_t)(c0 + row) * 256 + k0 + col);
        float4 hi = *(const float4*)(Wf + (size_t)(c0 + row) * 256 + k0 + col + 4);
        ushort4 o0 = { f2bf(lo.x), f2bf(lo.y), f2bf(lo.z), f2bf(lo.w) };
        ushort4 o1 = { f2bf(hi.x), f2bf(hi.y), f2bf(hi.z), f2bf(hi.w) };
        *(ushort4*)&Bs[u] = o0;
        *(ushort4*)&Bs[u + 4] = o1;
      }
    }
    __syncthreads();
    bf16x8 af[4], bfr[4];
    int rsel = lane & 15, ksel = (lane >> 4) * 8;
#pragma unroll
    for (int m = 0; m < 4; ++m)
      af[m] = *(bf16x8*)&As[(wr * 64 + m * 16 + rsel) * 32 + ksel];
#pragma unroll
    for (int n = 0; n < 4; ++n)
      bfr[n] = *(bf16x8*)&Bs[(wc * 64 + n * 16 + rsel) * 32 + ksel];
#pragma unroll
    for (int m = 0; m < 4; ++m)
#pragma unroll
      for (int n = 0; n < 4; ++n)
        acc[m][n] = __builtin_amdgcn_mfma_f32_16x16x32_bf16(af[m], bfr[n], acc[m][n], 0, 0, 0);
  }
  int rbase = r0 + wr * 64 + ((lane >> 4) * 4);
  int cbase = c0 + wc * 64 + (lane & 15);
#pragma unroll
  for (int n = 0; n < 4; ++n) {
    float bv = bias[cbase + n * 16];
#pragma unroll
    for (int m = 0; m < 4; ++m) {
#pragma unroll
      for (int j = 0; j < 4; ++j) {
        float v = acc[m][n][j] + bv;
        size_t idx = (size_t)(rbase + m * 16 + j) * 256 + (cbase + n * 16);
        if constexpr (sizeof(OutT) == 2) Y[idx] = (OutT)f2bf(v);
        else Y[idx] = (OutT)v;
      }
    }
  }
}

// ---------------- phase 1: QKV GEMM + column-sum partials + zero attn ----------------
__device__ __forceinline__ void phase1_body(
    const float* __restrict__ nodesL, const float* __restrict__ nodesR,
    const float* __restrict__ kptsR,
    const float* __restrict__ Wq, const float* __restrict__ bq,
    const float* __restrict__ Wk, const float* __restrict__ bk,
    const float* __restrict__ Wv, const float* __restrict__ bv,
    ushort* __restrict__ Qb, ushort* __restrict__ Kb, ushort* __restrict__ Vb,
    float* __restrict__ S16, float* __restrict__ sumU16,
    float* __restrict__ attn, char* smraw) {
  int bid = blockIdx.x, tid = threadIdx.x;
  ushort* As = (ushort*)smraw;
  ushort* Bs = (ushort*)(smraw + 8192);
  if (bid < 768) {
    int which = bid >> 8, blk = bid & 255;
    const float* A = (which == 0) ? nodesL : nodesR;
    const float* W = (which == 0) ? Wq : (which == 1) ? Wk : Wv;
    const float* bias = (which == 0) ? bq : (which == 1) ? bk : bv;
    ushort* Y = (which == 0) ? Qb : (which == 1) ? Kb : Vb;
    gemm_body<false, ushort>(A, W, bias, Y, blk, As, Bs);
  } else if (bid < 832) {
    int j = bid - 768;
    int b = j >> 4, ch = j & 15;
    int c4 = (tid & 63) * 4;
    int r0 = b * 4096 + ch * 256 + (tid >> 6);
    float4 acc = {0.f, 0.f, 0.f, 0.f};
    for (int k = 0; k < 64; ++k) {
      float4 v = *(const float4*)(nodesR + (size_t)(r0 + k * 4) * 256 + c4);
      acc.x += v.x; acc.y += v.y; acc.z += v.z; acc.w += v.w;
    }
    float4* red = (float4*)As;   // 4 KB scratch
    float* ured = (float*)Bs;    // 16 B scratch
    red[tid] = acc;
    float u = kptsR[(size_t)(b * 4096 + ch * 256 + tid) * 2];
    u = wredsum(u);
    if ((tid & 63) == 0) ured[tid >> 6] = u;
    __syncthreads();
    if (tid < 64) {
      float4 x = red[tid], y = red[tid + 64], z = red[tid + 128], w = red[tid + 192];
      float4 s = { x.x + y.x + z.x + w.x, x.y + y.y + z.y + w.y,
                   x.z + y.z + z.z + w.z, x.w + y.w + z.w + w.w };
      *(float4*)(S16 + (size_t)(b * 16 + ch) * 256 + tid * 4) = s;
    }
    if (tid == 0) sumU16[b * 16 + ch] = ured[0] + ured[1] + ured[2] + ured[3];
  }
  // streaming zero of attn: 262144 threads x 64 x 16 B = 268.4 MB
  f32x4 z = {0.f, 0.f, 0.f, 0.f};
  f32x4* dst = (f32x4*)attn;
  int g = bid * 256 + tid;
#pragma unroll
  for (int i = 0; i < 64; ++i)
    __builtin_nontemporal_store(z, dst + (size_t)g + (size_t)i * 262144);
}

// ---------------- phase 2: scan + softmax + PV + scatter (16 rows/block) ----------------
__device__ __forceinline__ void phase2_body(
    const float* __restrict__ kptsL, const float* __restrict__ kptsR,
    const ushort* __restrict__ Qb, const ushort* __restrict__ Kb,
    const ushort* __restrict__ Vb, const float* __restrict__ Wv,
    const float* __restrict__ bv, const float* __restrict__ S16,
    const float* __restrict__ sumU16, float* __restrict__ disp_out,
    float* __restrict__ conf_out, ushort* __restrict__ matched,
    float* __restrict__ attn, char* smraw) {
  float2* kR = (float2*)smraw;                               // 32768 B
  int   (*bufM)[CAP] = (int(*)[CAP])(smraw + 32768);         // 2048 B
  float (*bufD)[CAP] = (float(*)[CAP])(smraw + 34816);       // 2048 B
  float (*bufS)[CAP] = (float(*)[CAP])(smraw + 36864);       // 2048 B
  int bid = blockIdx.x, tid = threadIdx.x;
  int lane = tid & 63, wid = tid >> 6;
  int b = bid >> 8;
  int bb = b << 12;
  const float2* kRsrc = (const float2*)kptsR + (size_t)bb;
  for (int i = tid; i < 4096; i += 256) kR[i] = kRsrc[i];
  __syncthreads();
  unsigned long long lmask = (1ull << lane) - 1ull;

  for (int r = 0; r < 4; ++r) {
    int row = bid * 16 + wid * 4 + r;
    float* rowp = attn + (size_t)row * 4096;
    float2 kL = ((const float2*)kptsL)[(size_t)row];
    ushort4 qv = *(const ushort4*)(Qb + (size_t)row * 256 + lane * 4);
    float q0 = bf2f(qv.x), q1 = bf2f(qv.y), q2 = bf2f(qv.z), q3 = bf2f(qv.w);

    int cnt = 0;
#pragma unroll 4
    for (int m0 = 0; m0 < 4096; m0 += 64) {
      float2 kr = kR[m0 + lane];
      float dv = fabsf(kL.y - kr.y);
      float du = kL.x - kr.x;
      bool hit = (dv < 3.0f) && (du > 0.0f) && (du < 192.0f);
      unsigned long long bal = __ballot(hit);
      int pos = cnt + (int)__popcll(bal & lmask);
      if (hit && pos < CAP) { bufM[wid][pos] = m0 + lane; bufD[wid][pos] = du; }
      cnt += (int)__popcll(bal);
    }
    if (cnt > CAP) cnt = CAP;

    float conf, disp;
    if (cnt == 0) {
      // rare (~1 row per run): compute mean-V / mean-u in-wave
      conf = 0.f;
      float su = 0.f;
      for (int ch = 0; ch < 16; ++ch) su += sumU16[b * 16 + ch];
      disp = kL.x - su * (1.f / 4096.f);
      for (int k = lane; k < 256; k += 64) {
        float s = 0.f;
        for (int ch = 0; ch < 16; ++ch) s += S16[(size_t)(b * 16 + ch) * 256 + k];
        if (k < 128) bufD[wid][k] = s; else bufS[wid][k - 128] = s;
      }
      float mv[4];
#pragma unroll
      for (int j = 0; j < 4; ++j) {
        int c = lane * 4 + j;
        float acc = 0.f;
        for (int k = 0; k < 256; ++k) {
          float sv = (k < 128) ? bufD[wid][k] : bufS[wid][k - 128];
          acc += sv * Wv[(size_t)c * 256 + k];
        }
        mv[j] = acc * (1.f / 4096.f) + bv[c];
      }
      ushort4 st = { f2bf(mv[0]), f2bf(mv[1]), f2bf(mv[2]), f2bf(mv[3]) };
      *(ushort4*)(matched + (size_t)row * 256 + lane * 4) = st;
      const float fill = 1.f / 4096.f;
      f32x4 fv = { fill, fill, fill, fill };
      f32x4* dstp = (f32x4*)rowp;
#pragma unroll
      for (int jj = 0; jj < 16; ++jj)
        __builtin_nontemporal_store(fv, dstp + jj * 64 + lane);
    } else {
      // QK^T (4-way unrolled wave-cooperative dots)
      float mx = -1e30f;
      int i = 0;
      for (; i + 3 < cnt; i += 4) {
        int m0_ = bufM[wid][i], m1_ = bufM[wid][i + 1];
        int m2_ = bufM[wid][i + 2], m3_ = bufM[wid][i + 3];
        ushort4 k0 = *(const ushort4*)(Kb + ((size_t)(bb + m0_)) * 256 + lane * 4);
        ushort4 k1 = *(const ushort4*)(Kb + ((size_t)(bb + m1_)) * 256 + lane * 4);
        ushort4 k2 = *(const ushort4*)(Kb + ((size_t)(bb + m2_)) * 256 + lane * 4);
        ushort4 k3 = *(const ushort4*)(Kb + ((size_t)(bb + m3_)) * 256 + lane * 4);
        float p0 = q0 * bf2f(k0.x) + q1 * bf2f(k0.y) + q2 * bf2f(k0.z) + q3 * bf2f(k0.w);
        float p1 = q0 * bf2f(k1.x) + q1 * bf2f(k1.y) + q2 * bf2f(k1.z) + q3 * bf2f(k1.w);
        float p2 = q0 * bf2f(k2.x) + q1 * bf2f(k2.y) + q2 * bf2f(k2.z) + q3 * bf2f(k2.w);
        float p3 = q0 * bf2f(k3.x) + q1 * bf2f(k3.y) + q2 * bf2f(k3.z) + q3 * bf2f(k3.w);
#pragma unroll
        for (int o = 32; o; o >>= 1) {
          p0 += __shfl_xor(p0, o);
          p1 += __shfl_xor(p1, o);
          p2 += __shfl_xor(p2, o);
          p3 += __shfl_xor(p3, o);
        }
        float s0 = p0 * 0.0625f, s1 = p1 * 0.0625f;
        float s2 = p2 * 0.0625f, s3 = p3 * 0.0625f;
        if (lane == 0) {
          bufS[wid][i] = s0; bufS[wid][i + 1] = s1;
          bufS[wid][i + 2] = s2; bufS[wid][i + 3] = s3;
        }
        mx = fmaxf(mx, fmaxf(fmaxf(s0, s1), fmaxf(s2, s3)));
      }
      for (; i < cnt; ++i) {
        int ma = bufM[wid][i];
        ushort4 ka = *(const ushort4*)(Kb + ((size_t)(bb + ma)) * 256 + lane * 4);
        float pa = q0 * bf2f(ka.x) + q1 * bf2f(ka.y) + q2 * bf2f(ka.z) + q3 * bf2f(ka.w);
        pa = wredsum(pa);
        float sa = pa * 0.0625f;
        if (lane == 0) bufS[wid][i] = sa;
        mx = fmaxf(mx, sa);
      }
      // softmax
      float psum = 0.f, pdisp = 0.f;
      for (int k = lane; k < cnt; k += 64) {
        float e = expf(bufS[wid][k] - mx);
        bufS[wid][k] = e;
        psum += e;
        pdisp += e * bufD[wid][k];
      }
      psum = wredsum(psum);
      pdisp = wredsum(pdisp);
      float inv = 1.f / psum;
      disp = pdisp * inv;
      conf = 1.f;
      for (int k = lane; k < cnt; k += 64) bufS[wid][k] *= inv;
      // PV (4-way unrolled)
      float a0 = 0.f, a1 = 0.f, a2 = 0.f, a3 = 0.f;
      i = 0;
      for (; i + 3 < cnt; i += 4) {
        float w0 = bufS[wid][i], w1 = bufS[wid][i + 1];
        float w2 = bufS[wid][i + 2], w3 = bufS[wid][i + 3];
        int m0_ = bufM[wid][i], m1_ = bufM[wid][i + 1];
        int m2_ = bufM[wid][i + 2], m3_ = bufM[wid][i + 3];
        ushort4 v0 = *(const ushort4*)(Vb + ((size_t)(bb + m0_)) * 256 + lane * 4);
        ushort4 v1 = *(const ushort4*)(Vb + ((size_t)(bb + m1_)) * 256 + lane * 4);
        ushort4 v2 = *(const ushort4*)(Vb + ((size_t)(bb + m2_)) * 256 + lane * 4);
        ushort4 v3 = *(const ushort4*)(Vb + ((size_t)(bb + m3_)) * 256 + lane * 4);
        a0 += w0 * bf2f(v0.x) + w1 * bf2f(v1.x) + w2 * bf2f(v2.x) + w3 * bf2f(v3.x);
        a1 += w0 * bf2f(v0.y) + w1 * bf2f(v1.y) + w2 * bf2f(v2.y) + w3 * bf2f(v3.y);
        a2 += w0 * bf2f(v0.z) + w1 * bf2f(v1.z) + w2 * bf2f(v2.z) + w3 * bf2f(v3.z);
        a3 += w0 * bf2f(v0.w) + w1 * bf2f(v1.w) + w2 * bf2f(v2.w) + w3 * bf2f(v3.w);
      }
      for (; i < cnt; ++i) {
        float wa = bufS[wid][i];
        int ma = bufM[wid][i];
        ushort4 va = *(const ushort4*)(Vb + ((size_t)(bb + ma)) * 256 + lane * 4);
        a0 += wa * bf2f(va.x); a1 += wa * bf2f(va.y);
        a2 += wa * bf2f(va.z); a3 += wa * bf2f(va.w);
      }
      ushort4 st = { f2bf(a0), f2bf(a1), f2bf(a2), f2bf(a3) };
      *(ushort4*)(matched + (size_t)row * 256 + lane * 4) = st;
      // sparse scatter (zeros written in phase 1, ordered by grid sync / kernel boundary)
      for (int k = lane; k < cnt; k += 64)
        rowp[bufM[wid][k]] = bufS[wid][k];
    }
    if (lane == 0) { disp_out[row] = disp; conf_out[row] = conf; }
  }
}

// ---------------- mega kernel: PHASE 3 = all phases + grid syncs (cooperative) ----------------
template <int PHASE>
__global__ __launch_bounds__(256, 4) void mega(
    const float* nodesL, const float* nodesR,
    const float* kptsL, const float* kptsR,
    const float* Wq, const float* bq, const float* Wk, const float* bk,
    const float* Wv, const float* bv, const float* Wm, const float* bm,
    ushort* Qb, ushort* Kb, ushort* Vb, ushort* matched,
    float* S16, float* sumU16,
    float* out, float* disp_out, float* conf_out, float* attn) {
  __shared__ __align__(16) char smraw[38912];
  if constexpr (PHASE == 0 || PHASE == 3)
    phase1_body(nodesL, nodesR, kptsR, Wq, bq, Wk, bk, Wv, bv,
                Qb, Kb, Vb, S16, sumU16, attn, smraw);
  if constexpr (PHASE == 3) cg::this_grid().sync();
  if constexpr (PHASE == 1 || PHASE == 3)
    phase2_body(kptsL, kptsR, Qb, Kb, Vb, Wv, bv, S16, sumU16,
                disp_out, conf_out, matched, attn, smraw);
  if constexpr (PHASE == 3) cg::this_grid().sync();
  if constexpr (PHASE == 2 || PHASE == 3) {
    if (blockIdx.x < 256) {
      ushort* As = (ushort*)smraw;
      ushort* Bs = (ushort*)(smraw + 8192);
      gemm_body<true, float>(matched, Wm, bm, out, blockIdx.x, As, Bs);
    }
  }
}

extern "C" void kernel_launch(void* const* d_in, const int* in_sizes, int n_in,
                              void* d_out, int out_size, void* d_ws, size_t ws_size,
                              hipStream_t stream) {
  const float* nodes_L = (const float*)d_in[0];
  const float* nodes_R = (const float*)d_in[1];
  const float* kpts_L = (const float*)d_in[2];
  const float* kpts_R = (const float*)d_in[3];
  const float* Wq = (const float*)d_in[4];
  const float* bq = (const float*)d_in[5];
  const float* Wk = (const float*)d_in[6];
  const float* bk = (const float*)d_in[7];
  const float* Wv = (const float*)d_in[8];
  const float* bv = (const float*)d_in[9];
  const float* Wm = (const float*)d_in[10];
  const float* bm = (const float*)d_in[11];

  float* out = (float*)d_out;            // [4,4096,256]
  float* disp = out + 4194304;           // [4,4096,1]
  float* conf = disp + 16384;            // [4,4096,1]
  float* attn = conf + 16384;            // [4,4096,4096]

  char* ws = (char*)d_ws;
  ushort* Qb = (ushort*)(ws + 0);                 // 8 MB
  ushort* Kb = (ushort*)(ws + 8388608);           // 8 MB
  ushort* Vb = (ushort*)(ws + 16777216);          // 8 MB
  ushort* matched = (ushort*)(ws + 25165824);     // 8 MB
  float* S16 = (float*)(ws + 33554432);           // 64 KB partial column sums
  float* sumU16 = (float*)(ws + 33620224);        // 64 f32

  void* args[] = {
    (void*)&nodes_L, (void*)&nodes_R, (void*)&kpts_L, (void*)&kpts_R,
    (void*)&Wq, (void*)&bq, (void*)&Wk, (void*)&bk,
    (void*)&Wv, (void*)&bv, (void*)&Wm, (void*)&bm,
    (void*)&Qb, (void*)&Kb, (void*)&Vb, (void*)&matched,
    (void*)&S16, (void*)&sumU16,
    (void*)&out, (void*)&disp, (void*)&conf, (void*)&attn
  };
  hipError_t e = hipLaunchCooperativeKernel(
      reinterpret_cast<const void*>(&mega<3>), dim3(1024), dim3(256), args, 0, stream);
  if (e != hipSuccess) {
    // fallback: same phases as separate kernels (kernel boundaries = sync)
    mega<0><<<1024, 256, 0, stream>>>(nodes_L, nodes_R, kpts_L, kpts_R, Wq, bq, Wk, bk,
                                      Wv, bv, Wm, bm, Qb, Kb, Vb, matched, S16, sumU16,
                                      out, disp, conf, attn);
    mega<1><<<1024, 256, 0, stream>>>(nodes_L, nodes_R, kpts_L, kpts_R, Wq, bq, Wk, bk,
                                      Wv, bv, Wm, bm, Qb, Kb, Vb, matched, S16, sumU16,
                                      out, disp, conf, attn);
    mega<2><<<256, 256, 0, stream>>>(nodes_L, nodes_R, kpts_L, kpts_R, Wq, bq, Wk, bk,
                                     Wv, bv, Wm, bm, Qb, Kb, Vb, matched, S16, sumU16,
                                     out, disp, conf, attn);
  }
}

// Round 9
// 455.238 us; speedup vs baseline: 1.7392x; 1.7392x over previous
//
#include <hip/hip_runtime.h>
#include <stdint.h>

// B=4, N=M=4096, C=256
#define CAP 128   // max matches kept per row (lambda~9.5; P(cnt>128) ~ 1e-80)

typedef __attribute__((ext_vector_type(4))) float f32x4;
typedef __attribute__((ext_vector_type(8))) short bf16x8;

__device__ __forceinline__ float bf2f(ushort u) {
  return __uint_as_float(((unsigned)u) << 16);
}
__device__ __forceinline__ ushort f2bf(float f) {
  unsigned u = __float_as_uint(f);
  return (ushort)((u + 0x7fffu + ((u >> 16) & 1u)) >> 16);  // RNE
}
__device__ __forceinline__ float wredsum(float v) {
#pragma unroll
  for (int o = 32; o; o >>= 1) v += __shfl_xor(v, o);
  return v;
}

// ---------------- GEMM body: Y[r,o] = sum_c A[r,c]*W[o,c] + bias[o] ----------------
// A: [16384,256] bf16 (A_BF16) or f32 (converted during staging)
// W: [256,256] f32 row-major [out,in], converted to bf16 during staging
template <bool A_BF16, typename OutT>
__device__ __forceinline__ void gemm_body(const void* __restrict__ Av,
                                          const float* __restrict__ Wf,
                                          const float* __restrict__ bias,
                                          OutT* __restrict__ Y, int blk,
                                          ushort* As, ushort* Bs) {
  int tid = threadIdx.x;
  int lane = tid & 63, wid = tid >> 6;
  int bm = blk >> 1, bn = blk & 1;
  int r0 = bm * 128, c0 = bn * 128;
  int wr = wid >> 1, wc = wid & 1;
  f32x4 acc[4][4] = {};
  for (int k0 = 0; k0 < 256; k0 += 32) {
    __syncthreads();
#pragma unroll
    for (int p = 0; p < 2; ++p) {
      int u = p * 2048 + tid * 8;
      int row = u >> 5, col = u & 31;
      if constexpr (A_BF16) {
        *(bf16x8*)&As[u] =
            *(const bf16x8*)((const ushort*)Av + (size_t)(r0 + row) * 256 + k0 + col);
      } else {
        const float* Af = (const float*)Av;
        float4 lo = *(const float4*)(Af + (size_t)(r0 + row) * 256 + k0 + col);
        float4 hi = *(const float4*)(Af + (size_t)(r0 + row) * 256 + k0 + col + 4);
        ushort4 o0 = { f2bf(lo.x), f2bf(lo.y), f2bf(lo.z), f2bf(lo.w) };
        ushort4 o1 = { f2bf(hi.x), f2bf(hi.y), f2bf(hi.z), f2bf(hi.w) };
        *(ushort4*)&As[u] = o0;
        *(ushort4*)&As[u + 4] = o1;
      }
      {
        float4 lo = *(const float4*)(Wf + (size_t)(c0 + row) * 256 + k0 + col);
        float4 hi = *(const float4*)(Wf + (size_t)(c0 + row) * 256 + k0 + col + 4);
        ushort4 o0 = { f2bf(lo.x), f2bf(lo.y), f2bf(lo.z), f2bf(lo.w) };
        ushort4 o1 = { f2bf(hi.x), f2bf(hi.y), f2bf(hi.z), f2bf(hi.w) };
        *(ushort4*)&Bs[u] = o0;
        *(ushort4*)&Bs[u + 4] = o1;
      }
    }
    __syncthreads();
    bf16x8 af[4], bfr[4];
    int rsel = lane & 15, ksel = (lane >> 4) * 8;
#pragma unroll
    for (int m = 0; m < 4; ++m)
      af[m] = *(bf16x8*)&As[(wr * 64 + m * 16 + rsel) * 32 + ksel];
#pragma unroll
    for (int n = 0; n < 4; ++n)
      bfr[n] = *(bf16x8*)&Bs[(wc * 64 + n * 16 + rsel) * 32 + ksel];
#pragma unroll
    for (int m = 0; m < 4; ++m)
#pragma unroll
      for (int n = 0; n < 4; ++n)
        acc[m][n] = __builtin_amdgcn_mfma_f32_16x16x32_bf16(af[m], bfr[n], acc[m][n], 0, 0, 0);
  }
  int rbase = r0 + wr * 64 + ((lane >> 4) * 4);
  int cbase = c0 + wc * 64 + (lane & 15);
#pragma unroll
  for (int n = 0; n < 4; ++n) {
    float bv = bias[cbase + n * 16];
#pragma unroll
    for (int m = 0; m < 4; ++m) {
#pragma unroll
      for (int j = 0; j < 4; ++j) {
        float v = acc[m][n][j] + bv;
        size_t idx = (size_t)(rbase + m * 16 + j) * 256 + (cbase + n * 16);
        if constexpr (sizeof(OutT) == 2) Y[idx] = (OutT)f2bf(v);
        else Y[idx] = (OutT)v;
      }
    }
  }
}

// ---------------- fused front: QKV GEMM (0-767) || sum partials (768-831) || zero attn (768-2047) ----------------
__global__ __launch_bounds__(256, 2) void fused_front(
    const float* __restrict__ nodesL, const float* __restrict__ nodesR,
    const float* __restrict__ kptsR,
    const float* __restrict__ Wq, const float* __restrict__ bq,
    const float* __restrict__ Wk, const float* __restrict__ bk,
    const float* __restrict__ Wv, const float* __restrict__ bv,
    ushort* __restrict__ Qb, ushort* __restrict__ Kb, ushort* __restrict__ Vb,
    float* __restrict__ S16, float* __restrict__ sumU16,
    float* __restrict__ attn) {
  __shared__ __align__(16) ushort As[4096];
  __shared__ __align__(16) ushort Bs[4096];
  int bid = blockIdx.x, tid = threadIdx.x;
  if (bid < 768) {
    int which = bid >> 8, blk = bid & 255;
    const float* A = (which == 0) ? nodesL : nodesR;
    const float* W = (which == 0) ? Wq : (which == 1) ? Wk : Wv;
    const float* bias = (which == 0) ? bq : (which == 1) ? bk : bv;
    ushort* Y = (which == 0) ? Qb : (which == 1) ? Kb : Vb;
    gemm_body<false, ushort>(A, W, bias, Y, blk, As, Bs);
    return;
  }
  if (bid < 832) {
    // partial column sums of nodes_R + u-sums of kpts_R
    int j = bid - 768;
    int b = j >> 4, ch = j & 15;
    int c4 = (tid & 63) * 4;
    int r0 = b * 4096 + ch * 256 + (tid >> 6);
    float4 acc = {0.f, 0.f, 0.f, 0.f};
    for (int k = 0; k < 64; ++k) {
      float4 v = *(const float4*)(nodesR + (size_t)(r0 + k * 4) * 256 + c4);
      acc.x += v.x; acc.y += v.y; acc.z += v.z; acc.w += v.w;
    }
    float4* red = (float4*)As;   // 4 KB scratch
    float* ured = (float*)Bs;
    red[tid] = acc;
    float u = kptsR[(size_t)(b * 4096 + ch * 256 + tid) * 2];
    u = wredsum(u);
    if ((tid & 63) == 0) ured[tid >> 6] = u;
    __syncthreads();
    if (tid < 64) {
      float4 x = red[tid], y = red[tid + 64], z = red[tid + 128], w = red[tid + 192];
      float4 s = { x.x + y.x + z.x + w.x, x.y + y.y + z.y + w.y,
                   x.z + y.z + z.z + w.z, x.w + y.w + z.w + w.w };
      *(float4*)(S16 + (size_t)(b * 16 + ch) * 256 + tid * 4) = s;
    }
    if (tid == 0) sumU16[b * 16 + ch] = ured[0] + ured[1] + ured[2] + ured[3];
  }
  // streaming zero of attn (plain stores): 1280 blocks cover 16777216 f32x4 elems
  f32x4 z = {0.f, 0.f, 0.f, 0.f};
  f32x4* dst = (f32x4*)attn;
  const size_t stride = 1280u * 256u;
  for (size_t idx = (size_t)(bid - 768) * 256 + tid; idx < 16777216u; idx += stride)
    dst[idx] = z;
}

// ---------------- attn: scan + softmax + PV + sparse scatter (1 row/wave) ----------------
__global__ __launch_bounds__(512, 2) void attn_fused(
    const float* __restrict__ kptsL, const float* __restrict__ kptsR,
    const ushort* __restrict__ Qb, const ushort* __restrict__ Kb,
    const ushort* __restrict__ Vb, const float* __restrict__ Wv,
    const float* __restrict__ bv, const float* __restrict__ S16,
    const float* __restrict__ sumU16, float* __restrict__ disp_out,
    float* __restrict__ conf_out, ushort* __restrict__ matched,
    float* __restrict__ attn) {
  __shared__ float2 kR[4096];
  __shared__ int bufM[8][CAP];
  __shared__ float bufD[8][CAP];
  __shared__ float bufS[8][CAP];
  int tid = threadIdx.x, lane = tid & 63, wid = tid >> 6;
  int b = blockIdx.x >> 9;
  int n = ((blockIdx.x & 511) << 3) + wid;
  int row = (b << 12) + n;
  int bb = b << 12;
  float* rowp = attn + (size_t)row * 4096;

  const float2* kRsrc = (const float2*)kptsR + (size_t)bb;
  for (int i = tid; i < 4096; i += 512) kR[i] = kRsrc[i];
  __syncthreads();
  float2 kL = ((const float2*)kptsL)[(size_t)row];
  ushort4 qv = *(const ushort4*)(Qb + (size_t)row * 256 + lane * 4);
  float q0 = bf2f(qv.x), q1 = bf2f(qv.y), q2 = bf2f(qv.z), q3 = bf2f(qv.w);

  // ---- mask scan: branchless popcount-prefix hit compaction ----
  unsigned long long lmask = (1ull << lane) - 1ull;
  int cnt = 0;
#pragma unroll 4
  for (int m0 = 0; m0 < 4096; m0 += 64) {
    float2 kr = kR[m0 + lane];
    float dv = fabsf(kL.y - kr.y);
    float du = kL.x - kr.x;
    bool hit = (dv < 3.0f) && (du > 0.0f) && (du < 192.0f);
    unsigned long long bal = __ballot(hit);
    int pos = cnt + (int)__popcll(bal & lmask);
    if (hit && pos < CAP) { bufM[wid][pos] = m0 + lane; bufD[wid][pos] = du; }
    cnt += (int)__popcll(bal);
  }
  if (cnt > CAP) cnt = CAP;

  float conf, disp;
  if (cnt == 0) {
    // rare (~1 row per run): compute mean-V / mean-u in-wave from S16 partials
    conf = 0.f;
    float su = 0.f;
    for (int ch = 0; ch < 16; ++ch) su += sumU16[b * 16 + ch];
    disp = kL.x - su * (1.f / 4096.f);
    for (int k = lane; k < 256; k += 64) {
      float s = 0.f;
      for (int ch = 0; ch < 16; ++ch) s += S16[(size_t)(b * 16 + ch) * 256 + k];
      if (k < 128) bufD[wid][k] = s; else bufS[wid][k - 128] = s;
    }
    float mv[4];
#pragma unroll
    for (int j = 0; j < 4; ++j) {
      int c = lane * 4 + j;
      float acc = 0.f;
      for (int k = 0; k < 256; ++k) {
        float sv = (k < 128) ? bufD[wid][k] : bufS[wid][k - 128];
        acc += sv * Wv[(size_t)c * 256 + k];
      }
      mv[j] = acc * (1.f / 4096.f) + bv[c];
    }
    ushort4 st = { f2bf(mv[0]), f2bf(mv[1]), f2bf(mv[2]), f2bf(mv[3]) };
    *(ushort4*)(matched + (size_t)row * 256 + lane * 4) = st;
    const float fill = 1.f / 4096.f;
    f32x4 fv = { fill, fill, fill, fill };
    f32x4* dstp = (f32x4*)rowp;
#pragma unroll
    for (int jj = 0; jj < 16; ++jj)
      dstp[jj * 64 + lane] = fv;
  } else {
    // ---- QK^T (4-way unrolled wave-cooperative dots) ----
    float mx = -1e30f;
    int i = 0;
    for (; i + 3 < cnt; i += 4) {
      int m0_ = bufM[wid][i], m1_ = bufM[wid][i + 1];
      int m2_ = bufM[wid][i + 2], m3_ = bufM[wid][i + 3];
      ushort4 k0 = *(const ushort4*)(Kb + ((size_t)(bb + m0_)) * 256 + lane * 4);
      ushort4 k1 = *(const ushort4*)(Kb + ((size_t)(bb + m1_)) * 256 + lane * 4);
      ushort4 k2 = *(const ushort4*)(Kb + ((size_t)(bb + m2_)) * 256 + lane * 4);
      ushort4 k3 = *(const ushort4*)(Kb + ((size_t)(bb + m3_)) * 256 + lane * 4);
      float p0 = q0 * bf2f(k0.x) + q1 * bf2f(k0.y) + q2 * bf2f(k0.z) + q3 * bf2f(k0.w);
      float p1 = q0 * bf2f(k1.x) + q1 * bf2f(k1.y) + q2 * bf2f(k1.z) + q3 * bf2f(k1.w);
      float p2 = q0 * bf2f(k2.x) + q1 * bf2f(k2.y) + q2 * bf2f(k2.z) + q3 * bf2f(k2.w);
      float p3 = q0 * bf2f(k3.x) + q1 * bf2f(k3.y) + q2 * bf2f(k3.z) + q3 * bf2f(k3.w);
#pragma unroll
      for (int o = 32; o; o >>= 1) {
        p0 += __shfl_xor(p0, o);
        p1 += __shfl_xor(p1, o);
        p2 += __shfl_xor(p2, o);
        p3 += __shfl_xor(p3, o);
      }
      float s0 = p0 * 0.0625f, s1 = p1 * 0.0625f;
      float s2 = p2 * 0.0625f, s3 = p3 * 0.0625f;
      if (lane == 0) {
        bufS[wid][i] = s0; bufS[wid][i + 1] = s1;
        bufS[wid][i + 2] = s2; bufS[wid][i + 3] = s3;
      }
      mx = fmaxf(mx, fmaxf(fmaxf(s0, s1), fmaxf(s2, s3)));
    }
    for (; i < cnt; ++i) {
      int ma = bufM[wid][i];
      ushort4 ka = *(const ushort4*)(Kb + ((size_t)(bb + ma)) * 256 + lane * 4);
      float pa = q0 * bf2f(ka.x) + q1 * bf2f(ka.y) + q2 * bf2f(ka.z) + q3 * bf2f(ka.w);
      pa = wredsum(pa);
      float sa = pa * 0.0625f;
      if (lane == 0) bufS[wid][i] = sa;
      mx = fmaxf(mx, sa);
    }
    // ---- softmax ----
    float psum = 0.f, pdisp = 0.f;
    for (int k = lane; k < cnt; k += 64) {
      float e = expf(bufS[wid][k] - mx);
      bufS[wid][k] = e;
      psum += e;
      pdisp += e * bufD[wid][k];
    }
    psum = wredsum(psum);
    pdisp = wredsum(pdisp);
    float inv = 1.f / psum;
    disp = pdisp * inv;
    conf = 1.f;
    for (int k = lane; k < cnt; k += 64) bufS[wid][k] *= inv;
    // ---- PV (4-way unrolled) ----
    float a0 = 0.f, a1 = 0.f, a2 = 0.f, a3 = 0.f;
    i = 0;
    for (; i + 3 < cnt; i += 4) {
      float w0 = bufS[wid][i], w1 = bufS[wid][i + 1];
      float w2 = bufS[wid][i + 2], w3 = bufS[wid][i + 3];
      int m0_ = bufM[wid][i], m1_ = bufM[wid][i + 1];
      int m2_ = bufM[wid][i + 2], m3_ = bufM[wid][i + 3];
      ushort4 v0 = *(const ushort4*)(Vb + ((size_t)(bb + m0_)) * 256 + lane * 4);
      ushort4 v1 = *(const ushort4*)(Vb + ((size_t)(bb + m1_)) * 256 + lane * 4);
      ushort4 v2 = *(const ushort4*)(Vb + ((size_t)(bb + m2_)) * 256 + lane * 4);
      ushort4 v3 = *(const ushort4*)(Vb + ((size_t)(bb + m3_)) * 256 + lane * 4);
      a0 += w0 * bf2f(v0.x) + w1 * bf2f(v1.x) + w2 * bf2f(v2.x) + w3 * bf2f(v3.x);
      a1 += w0 * bf2f(v0.y) + w1 * bf2f(v1.y) + w2 * bf2f(v2.y) + w3 * bf2f(v3.y);
      a2 += w0 * bf2f(v0.z) + w1 * bf2f(v1.z) + w2 * bf2f(v2.z) + w3 * bf2f(v3.z);
      a3 += w0 * bf2f(v0.w) + w1 * bf2f(v1.w) + w2 * bf2f(v2.w) + w3 * bf2f(v3.w);
    }
    for (; i < cnt; ++i) {
      float wa = bufS[wid][i];
      int ma = bufM[wid][i];
      ushort4 va = *(const ushort4*)(Vb + ((size_t)(bb + ma)) * 256 + lane * 4);
      a0 += wa * bf2f(va.x); a1 += wa * bf2f(va.y);
      a2 += wa * bf2f(va.z); a3 += wa * bf2f(va.w);
    }
    ushort4 st = { f2bf(a0), f2bf(a1), f2bf(a2), f2bf(a3) };
    *(ushort4*)(matched + (size_t)row * 256 + lane * 4) = st;
    // ---- sparse scatter (zeros written by fused_front; kernel boundary orders) ----
    for (int k = lane; k < cnt; k += 64)
      rowp[bufM[wid][k]] = bufS[wid][k];
  }
  if (lane == 0) { disp_out[row] = disp; conf_out[row] = conf; }
}

__global__ __launch_bounds__(256, 2) void gemm_out(const ushort* __restrict__ A,
                                                   const float* __restrict__ Wm,
                                                   const float* __restrict__ bias,
                                                   float* __restrict__ Y) {
  __shared__ __align__(16) ushort As[4096];
  __shared__ __align__(16) ushort Bs[4096];
  gemm_body<true, float>(A, Wm, bias, Y, blockIdx.x, As, Bs);
}

extern "C" void kernel_launch(void* const* d_in, const int* in_sizes, int n_in,
                              void* d_out, int out_size, void* d_ws, size_t ws_size,
                              hipStream_t stream) {
  const float* nodes_L = (const float*)d_in[0];
  const float* nodes_R = (const float*)d_in[1];
  const float* kpts_L = (const float*)d_in[2];
  const float* kpts_R = (const float*)d_in[3];
  const float* Wq = (const float*)d_in[4];
  const float* bq = (const float*)d_in[5];
  const float* Wk = (const float*)d_in[6];
  const float* bk = (const float*)d_in[7];
  const float* Wv = (const float*)d_in[8];
  const float* bv = (const float*)d_in[9];
  const float* Wm = (const float*)d_in[10];
  const float* bm = (const float*)d_in[11];

  float* out = (float*)d_out;            // [4,4096,256]
  float* disp = out + 4194304;           // [4,4096,1]
  float* conf = disp + 16384;            // [4,4096,1]
  float* attn = conf + 16384;            // [4,4096,4096]

  char* ws = (char*)d_ws;
  ushort* Qb = (ushort*)(ws + 0);                 // 8 MB
  ushort* Kb = (ushort*)(ws + 8388608);           // 8 MB
  ushort* Vb = (ushort*)(ws + 16777216);          // 8 MB
  ushort* matched = (ushort*)(ws + 25165824);     // 8 MB
  float* S16 = (float*)(ws + 33554432);           // 64 KB partial column sums
  float* sumU16 = (float*)(ws + 33620224);        // 64 f32

  fused_front<<<2048, 256, 0, stream>>>(nodes_L, nodes_R, kpts_R, Wq, bq, Wk, bk,
                                        Wv, bv, Qb, Kb, Vb, S16, sumU16, attn);
  attn_fused<<<2048, 512, 0, stream>>>(kpts_L, kpts_R, Qb, Kb, Vb, Wv, bv, S16,
                                       sumU16, disp, conf, matched, attn);
  gemm_out<<<256, 256, 0, stream>>>(matched, Wm, bm, out);
}